// Round 16
// baseline (324.297 us; speedup 1.0000x reference)
//
#include <hip/hip_runtime.h>
#include <math.h>

#define NEG_SLOPE 0.2f
#define LN_EPS 1e-5f
#define BUCKET 48

typedef __attribute__((ext_vector_type(2))) float f32x2;

// DPP-based add: x += x permuted by CTRL (within 16-lane rows)
template <int CTRL>
__device__ __forceinline__ float dpp_add(float x) {
    int s = __builtin_amdgcn_update_dpp(0, __float_as_int(x), CTRL, 0xF, 0xF, true);
    return x + __int_as_float(s);
}
// full 16-lane row sum
__device__ __forceinline__ float row16_sum(float x) {
    x = dpp_add<0xB1>(x);   // quad_perm [1,0,3,2]
    x = dpp_add<0x4E>(x);   // quad_perm [2,3,0,1]
    x = dpp_add<0x124>(x);  // row_ror:4
    x = dpp_add<0x128>(x);  // row_ror:8
    return x;
}

// ---------- prep: 2 rows/wave GEMV (weight reads amortized) + buckets ----------
__global__ __launch_bounds__(256) void prep(
    const float* __restrict__ x,
    const float* __restrict__ W_l, const float* __restrict__ b_l,
    const float* __restrict__ W_r, const float* __restrict__ b_r,
    const float* __restrict__ W_res, const float* __restrict__ b_res,
    const float* __restrict__ W_e,
    const int* __restrict__ dist, const float* __restrict__ bph,
    float* __restrict__ xl, float* __restrict__ xr, float* __restrict__ xres_out,
    const int* __restrict__ ei, int* __restrict__ counts, int2* __restrict__ bucket,
    int n, int E_) {
    __shared__ float sWl[4096];
    __shared__ float sWr[4096];
    __shared__ float sWs[4096];
    __shared__ float sx[512];
    for (int i = threadIdx.x; i < 4096; i += 256) {
        sWl[i] = W_l[i]; sWr[i] = W_r[i]; sWs[i] = W_res[i];
    }
    int lane = threadIdx.x & 63;
    int w = threadIdx.x >> 6;
    float bl = b_l[lane], br = b_r[lane], bs = b_res[lane];
    float wsum = 0.0f;
#pragma unroll
    for (int k = 0; k < 16; ++k) wsum += W_e[k * 64 + lane];
    __syncthreads();
    for (int base = blockIdx.x * 8; base < n; base += gridDim.x * 8) {
        __syncthreads();
        {
            int idx = threadIdx.x;
            int row = base + (idx >> 6);
            if (row < n) sx[idx] = x[(size_t)row * 64 + (idx & 63)];
            idx += 256;
            row = base + (idx >> 6);
            if (row < n) sx[idx] = x[(size_t)row * 64 + (idx & 63)];
        }
        __syncthreads();
        int ra = base + w * 2;
        int rb = ra + 1;
        if (ra < n) {
            float al0 = bl, ar0 = br, as0 = bs;
            float al1 = bl, ar1 = br, as1 = bs;
            const float* xa = &sx[(w * 2) * 64];
#pragma unroll
            for (int k = 0; k < 64; ++k) {
                float wl = sWl[k * 64 + lane];
                float wr_ = sWr[k * 64 + lane];
                float ws_ = sWs[k * 64 + lane];
                float x0 = xa[k];
                float x1 = xa[k + 64];
                al0 = fmaf(x0, wl, al0); ar0 = fmaf(x0, wr_, ar0); as0 = fmaf(x0, ws_, as0);
                al1 = fmaf(x1, wl, al1); ar1 = fmaf(x1, wr_, ar1); as1 = fmaf(x1, ws_, as1);
            }
            {
                int hop = dist[ra];
                hop = hop < 0 ? 0 : (hop > 3 ? 3 : hop);
                float hb = 0.1f * bph[hop];
                xl[(size_t)ra * 64 + lane] = al0;
                xr[(size_t)ra * 64 + lane] = fmaf(hb, wsum, ar0);
                xres_out[(size_t)ra * 64 + lane] = as0;
            }
            if (rb < n) {
                int hop = dist[rb];
                hop = hop < 0 ? 0 : (hop > 3 ? 3 : hop);
                float hb = 0.1f * bph[hop];
                xl[(size_t)rb * 64 + lane] = al1;
                xr[(size_t)rb * 64 + lane] = fmaf(hb, wsum, ar1);
                xres_out[(size_t)rb * 64 + lane] = as1;
            }
        }
    }
    // direct bucket placement
    const int* di = ei + E_;
    for (int e = blockIdx.x * 256 + threadIdx.x; e < E_; e += gridDim.x * 256) {
        int dst = di[e];
        int src = ei[e];
        int pos = atomicAdd(&counts[dst], 1);
        pos = pos < BUCKET - 1 ? pos : BUCKET - 1;  // safety clamp
        bucket[(size_t)dst * BUCKET + pos] = make_int2(e, src);
    }
}

// ---------- fused gather: 3-phase pipeline, X depth 6, G (s_load) depth 3 ----------
#define LOAD_G(G, EA)                                                       \
    {                                                                       \
        int ec = __builtin_amdgcn_readfirstlane((EA).x);                    \
        const f32x2* p = (const f32x2*)(eattr + (size_t)ec * 16);           \
        _Pragma("unroll") for (int k = 0; k < 8; ++k) G[k] = p[k];          \
    }

#define PHASE(G, XA, XB, E, F, DEN, ACC, I)                                 \
    {                                                                       \
        f32x2 mm; mm.x = XA + base; mm.y = 0.0f;                            \
        _Pragma("unroll") for (int k = 0; k < 8; ++k)                       \
            mm = __builtin_elementwise_fma(G[k], w2[k], mm);                \
        float m = mm.x + mm.y;                                              \
        m = fmaxf(m, NEG_SLOPE * m);                                        \
        float l = row16_sum(m * attv);   /* attv pre-scaled by log2(e) */   \
        l = (I) < cnt ? l : -1e30f;                                         \
        float ex = __builtin_amdgcn_exp2f(l);                               \
        DEN += ex;                                                          \
        ACC = fmaf(ex, XA, ACC);                                            \
        XA = XB;                                                            \
        XB = xl[((unsigned)(F).y << 6) | lane];                             \
        LOAD_G(G, E);                                                       \
        E = F;                                                              \
        int nx = (I) + 9; nx = nx > last ? last : nx;                       \
        F = bk[nx];                                                         \
    }

__global__ __launch_bounds__(256) void fused_gather(
    const int* __restrict__ counts, const int2* __restrict__ bucket,
    const float* __restrict__ eattr,
    const float* __restrict__ W_e, const float* __restrict__ att,
    const float* __restrict__ xl, const float* __restrict__ xr,
    const float* __restrict__ bias,
    const float* __restrict__ gamma, const float* __restrict__ beta,
    float* out, int n) {
    int lane = threadIdx.x & 63;
    float attv = att[lane] * 1.44269504f;  // log2(e) folded: exp -> exp2
    float bi = bias[lane], g = gamma[lane], be = beta[lane];
    f32x2 w2[8];
#pragma unroll
    for (int k = 0; k < 8; ++k) {
        w2[k].x = W_e[(2 * k) * 64 + lane];
        w2[k].y = W_e[(2 * k + 1) * 64 + lane];
    }

    int wid = (blockIdx.x * blockDim.x + threadIdx.x) >> 6;
    int nw = (gridDim.x * blockDim.x) >> 6;
    for (int r = wid; r < n; r += nw) {
        int cnt = counts[r];            // vector load, r stays divergent
        float den0 = 0.0f, den1 = 0.0f, den2 = 0.0f;
        float acc0 = 0.0f, acc1 = 0.0f, acc2 = 0.0f;
        if (cnt > 0) {
            cnt = cnt < BUCKET ? cnt : BUCKET;
            float base = xr[((unsigned)r << 6) | lane];  // hop bias pre-folded
            const int2* bk = bucket + (size_t)r * BUCKET;
            int last = cnt - 1;
            int j1 = 1 > last ? last : 1;
            int j2 = 2 > last ? last : 2;
            int j3 = 3 > last ? last : 3;
            int j4 = 4 > last ? last : 4;
            int j5 = 5 > last ? last : 5;
            int j6 = 6 > last ? last : 6;
            int j7 = 7 > last ? last : 7;
            int j8 = 8 > last ? last : 8;
            int2 B0 = bk[0];
            int2 B1 = bk[j1];
            int2 B2 = bk[j2];
            int2 E0 = bk[j3];
            int2 E1 = bk[j4];
            int2 E2 = bk[j5];
            int2 F0 = bk[j6];
            int2 F1 = bk[j7];
            int2 F2 = bk[j8];
            float Xa0 = xl[((unsigned)B0.y << 6) | lane];
            float Xa1 = xl[((unsigned)B1.y << 6) | lane];
            float Xa2 = xl[((unsigned)B2.y << 6) | lane];
            float Xb0 = xl[((unsigned)E0.y << 6) | lane];
            float Xb1 = xl[((unsigned)E1.y << 6) | lane];
            float Xb2 = xl[((unsigned)E2.y << 6) | lane];
            f32x2 G0[8], G1[8], G2[8];
            LOAD_G(G0, B0);
            LOAD_G(G1, B1);
            LOAD_G(G2, B2);
            for (int i = 0; i < cnt; i += 3) {
                PHASE(G0, Xa0, Xb0, E0, F0, den0, acc0, i)
                PHASE(G1, Xa1, Xb1, E1, F1, den1, acc1, i + 1)
                PHASE(G2, Xa2, Xb2, E2, F2, den2, acc2, i + 2)
            }
        }
        float den = (den0 + den1) + den2;
        float acc = (acc0 + acc1) + acc2;
        float v = acc / (den + 1e-16f) + bi;
        // LayerNorm over 64 features
        float s = row16_sum(v);
        s += __shfl_xor(s, 16, 64);
        s += __shfl_xor(s, 32, 64);
        float mu = s * (1.0f / 64.0f);
        float dd = v - mu;
        float q = row16_sum(dd * dd);
        q += __shfl_xor(q, 16, 64);
        q += __shfl_xor(q, 32, 64);
        float var = q * (1.0f / 64.0f);
        float nv = dd * rsqrtf(var + LN_EPS) * g + be;
        unsigned idx = ((unsigned)r << 6) | lane;
        out[idx] = nv + out[idx];  // residual was staged in out by prep
    }
}

extern "C" void kernel_launch(void* const* d_in, const int* in_sizes, int n_in,
                              void* d_out, int out_size, void* d_ws, size_t ws_size,
                              hipStream_t stream) {
    const float* x     = (const float*)d_in[0];
    const int*   ei    = (const int*)d_in[1];
    const float* eattr = (const float*)d_in[2];
    const int*   dist  = (const int*)d_in[3];
    const float* W_l   = (const float*)d_in[4];
    const float* b_l   = (const float*)d_in[5];
    const float* W_r   = (const float*)d_in[6];
    const float* b_r   = (const float*)d_in[7];
    const float* W_e   = (const float*)d_in[8];
    const float* att   = (const float*)d_in[9];
    const float* bias  = (const float*)d_in[10];
    const float* gamma = (const float*)d_in[11];
    const float* beta  = (const float*)d_in[12];
    const float* W_res = (const float*)d_in[13];
    const float* b_res = (const float*)d_in[14];
    const float* bph   = (const float*)d_in[15];

    int n  = in_sizes[0] / 64;
    int E_ = in_sizes[1] / 2;
    float* out = (float*)d_out;

    char* ws = (char*)d_ws;
    float* xl     = (float*)ws; ws += (size_t)n * 64 * 4;
    float* xr     = (float*)ws; ws += (size_t)n * 64 * 4;
    int2*  bucket = (int2*)ws;  ws += (size_t)n * BUCKET * 8;
    int*   counts = (int*)ws;   ws += (size_t)n * 4;

    hipMemsetAsync(counts, 0, (size_t)n * 4, stream);
    prep<<<2048, 256, 0, stream>>>(x, W_l, b_l, W_r, b_r, W_res, b_res, W_e,
                                   dist, bph, xl, xr, out, ei, counts, bucket, n, E_);
    fused_gather<<<4096, 256, 0, stream>>>(counts, bucket, eattr,
                                           W_e, att, xl, xr,
                                           bias, gamma, beta, out, n);
}

// Round 17
// 286.206 us; speedup vs baseline: 1.1331x; 1.1331x over previous
//
#include <hip/hip_runtime.h>
#include <math.h>

#define NEG_SLOPE 0.2f
#define LN_EPS 1e-5f
#define BUCKET 48

typedef __attribute__((ext_vector_type(2))) float f32x2;

// DPP-based add: x += x permuted by CTRL (within 16-lane rows)
template <int CTRL>
__device__ __forceinline__ float dpp_add(float x) {
    int s = __builtin_amdgcn_update_dpp(0, __float_as_int(x), CTRL, 0xF, 0xF, true);
    return x + __int_as_float(s);
}
// full 16-lane row sum
__device__ __forceinline__ float row16_sum(float x) {
    x = dpp_add<0xB1>(x);   // quad_perm [1,0,3,2]
    x = dpp_add<0x4E>(x);   // quad_perm [2,3,0,1]
    x = dpp_add<0x124>(x);  // row_ror:4
    x = dpp_add<0x128>(x);  // row_ror:8
    return x;
}

// ---------- prep (FROZEN, exact R12/R15 form): transforms + hop fold + buckets -------
__global__ __launch_bounds__(256) void prep(
    const float* __restrict__ x,
    const float* __restrict__ W_l, const float* __restrict__ b_l,
    const float* __restrict__ W_r, const float* __restrict__ b_r,
    const float* __restrict__ W_res, const float* __restrict__ b_res,
    const float* __restrict__ W_e,
    const int* __restrict__ dist, const float* __restrict__ bph,
    float* __restrict__ xl, float* __restrict__ xr, float* __restrict__ xres_out,
    const int* __restrict__ ei, int* __restrict__ counts, int2* __restrict__ bucket,
    int n, int E_) {
    __shared__ float sWl[4096];
    __shared__ float sWr[4096];
    __shared__ float sWs[4096];
    __shared__ float sx[256];
    for (int i = threadIdx.x; i < 4096; i += 256) {
        sWl[i] = W_l[i]; sWr[i] = W_r[i]; sWs[i] = W_res[i];
    }
    int lane = threadIdx.x & 63;
    int w = threadIdx.x >> 6;
    float bl = b_l[lane], br = b_r[lane], bs = b_res[lane];
    float wsum = 0.0f;
#pragma unroll
    for (int k = 0; k < 16; ++k) wsum += W_e[k * 64 + lane];
    __syncthreads();
    for (int base = blockIdx.x * 4; base < n; base += gridDim.x * 4) {
        __syncthreads();
        int r = base + w;
        if (r < n) sx[threadIdx.x] = x[(size_t)r * 64 + lane];
        __syncthreads();
        if (r < n) {
            float al = bl, ar = br, as_ = bs;
            const float* xv = &sx[w * 64];
#pragma unroll
            for (int k = 0; k < 64; ++k) {
                float xk = xv[k];
                al = fmaf(xk, sWl[k * 64 + lane], al);
                ar = fmaf(xk, sWr[k * 64 + lane], ar);
                as_ = fmaf(xk, sWs[k * 64 + lane], as_);
            }
            int hop = dist[r];
            hop = hop < 0 ? 0 : (hop > 3 ? 3 : hop);
            float hb = 0.1f * bph[hop];
            xl[(size_t)r * 64 + lane] = al;
            xr[(size_t)r * 64 + lane] = fmaf(hb, wsum, ar);  // hop bias folded in
            xres_out[(size_t)r * 64 + lane] = as_;           // residual staged in d_out
        }
    }
    // direct bucket placement
    const int* di = ei + E_;
    for (int e = blockIdx.x * 256 + threadIdx.x; e < E_; e += gridDim.x * 256) {
        int dst = di[e];
        int src = ei[e];
        int pos = atomicAdd(&counts[dst], 1);
        pos = pos < BUCKET - 1 ? pos : BUCKET - 1;  // safety clamp
        bucket[(size_t)dst * BUCKET + pos] = make_int2(e, src);
    }
}

// ---------- fused gather: 3-phase pipeline, X depth 6, G (s_load) depth 3 ----------
#define LOAD_G(G, EA)                                                       \
    {                                                                       \
        int ec = __builtin_amdgcn_readfirstlane((EA).x);                    \
        const f32x2* p = (const f32x2*)(eattr + (size_t)ec * 16);           \
        _Pragma("unroll") for (int k = 0; k < 8; ++k) G[k] = p[k];          \
    }

#define PHASE(G, XA, XB, E, F, DEN, ACC, I)                                 \
    {                                                                       \
        f32x2 mm; mm.x = XA + base; mm.y = 0.0f;                            \
        _Pragma("unroll") for (int k = 0; k < 8; ++k)                       \
            mm = __builtin_elementwise_fma(G[k], w2[k], mm);                \
        float m = mm.x + mm.y;                                              \
        m = fmaxf(m, NEG_SLOPE * m);                                        \
        float l = row16_sum(m * attv);   /* attv pre-scaled by log2(e) */   \
        l = (I) < cnt ? l : -1e30f;                                         \
        float ex = __builtin_amdgcn_exp2f(l);                               \
        DEN += ex;                                                          \
        ACC = fmaf(ex, XA, ACC);                                            \
        XA = XB;                                                            \
        XB = xl[((unsigned)(F).y << 6) | lane];                             \
        LOAD_G(G, E);                                                       \
        E = F;                                                              \
        int nx = (I) + 9; nx = nx > last ? last : nx;                       \
        F = bk[nx];                                                         \
    }

__global__ __launch_bounds__(256) void fused_gather(
    const int* __restrict__ counts, const int2* __restrict__ bucket,
    const float* __restrict__ eattr,
    const float* __restrict__ W_e, const float* __restrict__ att,
    const float* __restrict__ xl, const float* __restrict__ xr,
    const float* __restrict__ bias,
    const float* __restrict__ gamma, const float* __restrict__ beta,
    float* out, int n) {
    int lane = threadIdx.x & 63;
    float attv = att[lane] * 1.44269504f;  // log2(e) folded: exp -> exp2
    float bi = bias[lane], g = gamma[lane], be = beta[lane];
    f32x2 w2[8];
#pragma unroll
    for (int k = 0; k < 8; ++k) {
        w2[k].x = W_e[(2 * k) * 64 + lane];
        w2[k].y = W_e[(2 * k + 1) * 64 + lane];
    }

    int wid = (blockIdx.x * blockDim.x + threadIdx.x) >> 6;
    int nw = (gridDim.x * blockDim.x) >> 6;
    for (int r = wid; r < n; r += nw) {
        int cnt = counts[r];            // vector load, r stays divergent
        float den0 = 0.0f, den1 = 0.0f, den2 = 0.0f;
        float acc0 = 0.0f, acc1 = 0.0f, acc2 = 0.0f;
        if (cnt > 0) {
            cnt = cnt < BUCKET ? cnt : BUCKET;
            float base = xr[((unsigned)r << 6) | lane];  // hop bias pre-folded
            const int2* bk = bucket + (size_t)r * BUCKET;
            int last = cnt - 1;
            int j1 = 1 > last ? last : 1;
            int j2 = 2 > last ? last : 2;
            int j3 = 3 > last ? last : 3;
            int j4 = 4 > last ? last : 4;
            int j5 = 5 > last ? last : 5;
            int j6 = 6 > last ? last : 6;
            int j7 = 7 > last ? last : 7;
            int j8 = 8 > last ? last : 8;
            int2 B0 = bk[0];
            int2 B1 = bk[j1];
            int2 B2 = bk[j2];
            int2 E0 = bk[j3];
            int2 E1 = bk[j4];
            int2 E2 = bk[j5];
            int2 F0 = bk[j6];
            int2 F1 = bk[j7];
            int2 F2 = bk[j8];
            float Xa0 = xl[((unsigned)B0.y << 6) | lane];
            float Xa1 = xl[((unsigned)B1.y << 6) | lane];
            float Xa2 = xl[((unsigned)B2.y << 6) | lane];
            float Xb0 = xl[((unsigned)E0.y << 6) | lane];
            float Xb1 = xl[((unsigned)E1.y << 6) | lane];
            float Xb2 = xl[((unsigned)E2.y << 6) | lane];
            f32x2 G0[8], G1[8], G2[8];
            LOAD_G(G0, B0);
            LOAD_G(G1, B1);
            LOAD_G(G2, B2);
            for (int i = 0; i < cnt; i += 3) {
                PHASE(G0, Xa0, Xb0, E0, F0, den0, acc0, i)
                PHASE(G1, Xa1, Xb1, E1, F1, den1, acc1, i + 1)
                PHASE(G2, Xa2, Xb2, E2, F2, den2, acc2, i + 2)
            }
        }
        float den = (den0 + den1) + den2;
        float acc = (acc0 + acc1) + acc2;
        float v = acc / (den + 1e-16f) + bi;
        // LayerNorm over 64 features
        float s = row16_sum(v);
        s += __shfl_xor(s, 16, 64);
        s += __shfl_xor(s, 32, 64);
        float mu = s * (1.0f / 64.0f);
        float dd = v - mu;
        float q = row16_sum(dd * dd);
        q += __shfl_xor(q, 16, 64);
        q += __shfl_xor(q, 32, 64);
        float var = q * (1.0f / 64.0f);
        float nv = dd * rsqrtf(var + LN_EPS) * g + be;
        unsigned idx = ((unsigned)r << 6) | lane;
        out[idx] = nv + out[idx];  // residual was staged in out by prep
    }
}

extern "C" void kernel_launch(void* const* d_in, const int* in_sizes, int n_in,
                              void* d_out, int out_size, void* d_ws, size_t ws_size,
                              hipStream_t stream) {
    const float* x     = (const float*)d_in[0];
    const int*   ei    = (const int*)d_in[1];
    const float* eattr = (const float*)d_in[2];
    const int*   dist  = (const int*)d_in[3];
    const float* W_l   = (const float*)d_in[4];
    const float* b_l   = (const float*)d_in[5];
    const float* W_r   = (const float*)d_in[6];
    const float* b_r   = (const float*)d_in[7];
    const float* W_e   = (const float*)d_in[8];
    const float* att   = (const float*)d_in[9];
    const float* bias  = (const float*)d_in[10];
    const float* gamma = (const float*)d_in[11];
    const float* beta  = (const float*)d_in[12];
    const float* W_res = (const float*)d_in[13];
    const float* b_res = (const float*)d_in[14];
    const float* bph   = (const float*)d_in[15];

    int n  = in_sizes[0] / 64;
    int E_ = in_sizes[1] / 2;
    float* out = (float*)d_out;

    char* ws = (char*)d_ws;
    float* xl     = (float*)ws; ws += (size_t)n * 64 * 4;
    float* xr     = (float*)ws; ws += (size_t)n * 64 * 4;
    int2*  bucket = (int2*)ws;  ws += (size_t)n * BUCKET * 8;
    int*   counts = (int*)ws;   ws += (size_t)n * 4;

    hipMemsetAsync(counts, 0, (size_t)n * 4, stream);
    prep<<<2048, 256, 0, stream>>>(x, W_l, b_l, W_r, b_r, W_res, b_res, W_e,
                                   dist, bph, xl, xr, out, ei, counts, bucket, n, E_);
    fused_gather<<<4096, 256, 0, stream>>>(counts, bucket, eattr,
                                           W_e, att, xl, xr,
                                           bias, gamma, beta, out, n);
}

// Round 18
// 279.221 us; speedup vs baseline: 1.1614x; 1.0250x over previous
//
#include <hip/hip_runtime.h>
#include <math.h>

#define NEG_SLOPE 0.2f
#define LN_EPS 1e-5f
#define BUCKET 48

typedef __attribute__((ext_vector_type(2))) float f32x2;

// DPP-based add: x += x permuted by CTRL (within 16-lane rows)
template <int CTRL>
__device__ __forceinline__ float dpp_add(float x) {
    int s = __builtin_amdgcn_update_dpp(0, __float_as_int(x), CTRL, 0xF, 0xF, true);
    return x + __int_as_float(s);
}
// full 16-lane row sum
__device__ __forceinline__ float row16_sum(float x) {
    x = dpp_add<0xB1>(x);   // quad_perm [1,0,3,2]
    x = dpp_add<0x4E>(x);   // quad_perm [2,3,0,1]
    x = dpp_add<0x124>(x);  // row_ror:4
    x = dpp_add<0x128>(x);  // row_ror:8
    return x;
}

// ---------- prep (FROZEN, exact R12/R15 form): transforms + hop fold + buckets -------
__global__ __launch_bounds__(256) void prep(
    const float* __restrict__ x,
    const float* __restrict__ W_l, const float* __restrict__ b_l,
    const float* __restrict__ W_r, const float* __restrict__ b_r,
    const float* __restrict__ W_res, const float* __restrict__ b_res,
    const float* __restrict__ W_e,
    const int* __restrict__ dist, const float* __restrict__ bph,
    float* __restrict__ xl, float* __restrict__ xr, float* __restrict__ xres_out,
    const int* __restrict__ ei, int* __restrict__ counts, int2* __restrict__ bucket,
    int n, int E_) {
    __shared__ float sWl[4096];
    __shared__ float sWr[4096];
    __shared__ float sWs[4096];
    __shared__ float sx[256];
    for (int i = threadIdx.x; i < 4096; i += 256) {
        sWl[i] = W_l[i]; sWr[i] = W_r[i]; sWs[i] = W_res[i];
    }
    int lane = threadIdx.x & 63;
    int w = threadIdx.x >> 6;
    float bl = b_l[lane], br = b_r[lane], bs = b_res[lane];
    float wsum = 0.0f;
#pragma unroll
    for (int k = 0; k < 16; ++k) wsum += W_e[k * 64 + lane];
    __syncthreads();
    for (int base = blockIdx.x * 4; base < n; base += gridDim.x * 4) {
        __syncthreads();
        int r = base + w;
        if (r < n) sx[threadIdx.x] = x[(size_t)r * 64 + lane];
        __syncthreads();
        if (r < n) {
            float al = bl, ar = br, as_ = bs;
            const float* xv = &sx[w * 64];
#pragma unroll
            for (int k = 0; k < 64; ++k) {
                float xk = xv[k];
                al = fmaf(xk, sWl[k * 64 + lane], al);
                ar = fmaf(xk, sWr[k * 64 + lane], ar);
                as_ = fmaf(xk, sWs[k * 64 + lane], as_);
            }
            int hop = dist[r];
            hop = hop < 0 ? 0 : (hop > 3 ? 3 : hop);
            float hb = 0.1f * bph[hop];
            xl[(size_t)r * 64 + lane] = al;
            xr[(size_t)r * 64 + lane] = fmaf(hb, wsum, ar);  // hop bias folded in
            xres_out[(size_t)r * 64 + lane] = as_;           // residual staged in d_out
        }
    }
    // direct bucket placement
    const int* di = ei + E_;
    for (int e = blockIdx.x * 256 + threadIdx.x; e < E_; e += gridDim.x * 256) {
        int dst = di[e];
        int src = ei[e];
        int pos = atomicAdd(&counts[dst], 1);
        pos = pos < BUCKET - 1 ? pos : BUCKET - 1;  // safety clamp
        bucket[(size_t)dst * BUCKET + pos] = make_int2(e, src);
    }
}

// ---------- fused gather: 3 consumes then batched refills (one drain per 3 edges) ----
#define LOAD_G(G, EA)                                                       \
    {                                                                       \
        int ec = __builtin_amdgcn_readfirstlane((EA).x);                    \
        const f32x2* p = (const f32x2*)(eattr + (size_t)ec * 16);           \
        _Pragma("unroll") for (int k = 0; k < 8; ++k) G[k] = p[k];          \
    }

#define COMPUTE(G, XA, DEN, ACC, I)                                         \
    {                                                                       \
        f32x2 mm; mm.x = XA + base; mm.y = 0.0f;                            \
        _Pragma("unroll") for (int k = 0; k < 8; ++k)                       \
            mm = __builtin_elementwise_fma(G[k], w2[k], mm);                \
        float m = mm.x + mm.y;                                              \
        m = fmaxf(m, NEG_SLOPE * m);                                        \
        float l = row16_sum(m * attv);   /* attv pre-scaled by log2(e) */   \
        l = (I) < cnt ? l : -1e30f;                                         \
        float ex = __builtin_amdgcn_exp2f(l);                               \
        DEN += ex;                                                          \
        ACC = fmaf(ex, XA, ACC);                                            \
    }

__global__ __launch_bounds__(256) void fused_gather(
    const int* __restrict__ counts, const int2* __restrict__ bucket,
    const float* __restrict__ eattr,
    const float* __restrict__ W_e, const float* __restrict__ att,
    const float* __restrict__ xl, const float* __restrict__ xr,
    const float* __restrict__ bias,
    const float* __restrict__ gamma, const float* __restrict__ beta,
    float* out, int n) {
    int lane = threadIdx.x & 63;
    float attv = att[lane] * 1.44269504f;  // log2(e) folded: exp -> exp2
    float bi = bias[lane], g = gamma[lane], be = beta[lane];
    f32x2 w2[8];
#pragma unroll
    for (int k = 0; k < 8; ++k) {
        w2[k].x = W_e[(2 * k) * 64 + lane];
        w2[k].y = W_e[(2 * k + 1) * 64 + lane];
    }

    int wid = (blockIdx.x * blockDim.x + threadIdx.x) >> 6;
    int nw = (gridDim.x * blockDim.x) >> 6;
    for (int r = wid; r < n; r += nw) {
        int cnt = counts[r];            // vector load, r stays divergent
        float den0 = 0.0f, den1 = 0.0f, den2 = 0.0f;
        float acc0 = 0.0f, acc1 = 0.0f, acc2 = 0.0f;
        if (cnt > 0) {
            cnt = cnt < BUCKET ? cnt : BUCKET;
            float base = xr[((unsigned)r << 6) | lane];  // hop bias pre-folded
            const int2* bk = bucket + (size_t)r * BUCKET;
            int last = cnt - 1;
            int j1 = 1 > last ? last : 1;
            int j2 = 2 > last ? last : 2;
            int j3 = 3 > last ? last : 3;
            int j4 = 4 > last ? last : 4;
            int j5 = 5 > last ? last : 5;
            int j6 = 6 > last ? last : 6;
            int j7 = 7 > last ? last : 7;
            int j8 = 8 > last ? last : 8;
            int2 B0 = bk[0];
            int2 B1 = bk[j1];
            int2 B2 = bk[j2];
            int2 E0 = bk[j3];
            int2 E1 = bk[j4];
            int2 E2 = bk[j5];
            int2 F0 = bk[j6];
            int2 F1 = bk[j7];
            int2 F2 = bk[j8];
            float Xa0 = xl[((unsigned)B0.y << 6) | lane];
            float Xa1 = xl[((unsigned)B1.y << 6) | lane];
            float Xa2 = xl[((unsigned)B2.y << 6) | lane];
            float Xb0 = xl[((unsigned)E0.y << 6) | lane];
            float Xb1 = xl[((unsigned)E1.y << 6) | lane];
            float Xb2 = xl[((unsigned)E2.y << 6) | lane];
            f32x2 G0[8], G1[8], G2[8];
            LOAD_G(G0, B0);
            LOAD_G(G1, B1);
            LOAD_G(G2, B2);
            for (int i = 0; i < cnt; i += 3) {
                // ---- consume 3 edges (single lgkmcnt drain at first G use) ----
                COMPUTE(G0, Xa0, den0, acc0, i)
                COMPUTE(G1, Xa1, den1, acc1, i + 1)
                COMPUTE(G2, Xa2, den2, acc2, i + 2)
                // ---- batched refills for the next iteration ----
                Xa0 = Xb0; Xb0 = xl[((unsigned)F0.y << 6) | lane];
                Xa1 = Xb1; Xb1 = xl[((unsigned)F1.y << 6) | lane];
                Xa2 = Xb2; Xb2 = xl[((unsigned)F2.y << 6) | lane];
                LOAD_G(G0, E0);
                LOAD_G(G1, E1);
                LOAD_G(G2, E2);
                E0 = F0; E1 = F1; E2 = F2;
                int n0 = i + 9;  n0 = n0 > last ? last : n0;
                int n1 = i + 10; n1 = n1 > last ? last : n1;
                int n2 = i + 11; n2 = n2 > last ? last : n2;
                F0 = bk[n0];
                F1 = bk[n1];
                F2 = bk[n2];
            }
        }
        float den = (den0 + den1) + den2;
        float acc = (acc0 + acc1) + acc2;
        float v = acc / (den + 1e-16f) + bi;
        // LayerNorm over 64 features
        float s = row16_sum(v);
        s += __shfl_xor(s, 16, 64);
        s += __shfl_xor(s, 32, 64);
        float mu = s * (1.0f / 64.0f);
        float dd = v - mu;
        float q = row16_sum(dd * dd);
        q += __shfl_xor(q, 16, 64);
        q += __shfl_xor(q, 32, 64);
        float var = q * (1.0f / 64.0f);
        float nv = dd * rsqrtf(var + LN_EPS) * g + be;
        unsigned idx = ((unsigned)r << 6) | lane;
        out[idx] = nv + out[idx];  // residual was staged in out by prep
    }
}

extern "C" void kernel_launch(void* const* d_in, const int* in_sizes, int n_in,
                              void* d_out, int out_size, void* d_ws, size_t ws_size,
                              hipStream_t stream) {
    const float* x     = (const float*)d_in[0];
    const int*   ei    = (const int*)d_in[1];
    const float* eattr = (const float*)d_in[2];
    const int*   dist  = (const int*)d_in[3];
    const float* W_l   = (const float*)d_in[4];
    const float* b_l   = (const float*)d_in[5];
    const float* W_r   = (const float*)d_in[6];
    const float* b_r   = (const float*)d_in[7];
    const float* W_e   = (const float*)d_in[8];
    const float* att   = (const float*)d_in[9];
    const float* bias  = (const float*)d_in[10];
    const float* gamma = (const float*)d_in[11];
    const float* beta  = (const float*)d_in[12];
    const float* W_res = (const float*)d_in[13];
    const float* b_res = (const float*)d_in[14];
    const float* bph   = (const float*)d_in[15];

    int n  = in_sizes[0] / 64;
    int E_ = in_sizes[1] / 2;
    float* out = (float*)d_out;

    char* ws = (char*)d_ws;
    float* xl     = (float*)ws; ws += (size_t)n * 64 * 4;
    float* xr     = (float*)ws; ws += (size_t)n * 64 * 4;
    int2*  bucket = (int2*)ws;  ws += (size_t)n * BUCKET * 8;
    int*   counts = (int*)ws;   ws += (size_t)n * 4;

    hipMemsetAsync(counts, 0, (size_t)n * 4, stream);
    prep<<<2048, 256, 0, stream>>>(x, W_l, b_l, W_r, b_r, W_res, b_res, W_e,
                                   dist, bph, xl, xr, out, ei, counts, bucket, n, E_);
    fused_gather<<<4096, 256, 0, stream>>>(counts, bucket, eattr,
                                           W_e, att, xl, xr,
                                           bias, gamma, beta, out, n);
}